// Round 8
// baseline (434.595 us; speedup 1.0000x reference)
//
#include <hip/hip_runtime.h>
#include <math.h>

#define TOK 32768
#define CH  256
#define HIDN 1024
#define NE  8
#define BE  10240
#define CNT_STRIDE 64

typedef __attribute__((ext_vector_type(8))) short bf16x8;
typedef __attribute__((ext_vector_type(4))) float f32x4;

__device__ __forceinline__ unsigned short f2bf(float f) {
    unsigned u = __builtin_bit_cast(unsigned, f);
    unsigned r = 0x7FFFu + ((u >> 16) & 1u);
    return (unsigned short)((u + r) >> 16);
}
__device__ __forceinline__ float bf2f(unsigned short u) {
    return __builtin_bit_cast(float, (unsigned)u << 16);
}
__device__ __forceinline__ unsigned pk8_lo(float a, float b, unsigned old) {
    return (unsigned)__builtin_amdgcn_cvt_pk_fp8_f32(a, b, (int)old, false);
}
__device__ __forceinline__ unsigned pk8_hi(float a, float b, unsigned old) {
    return (unsigned)__builtin_amdgcn_cvt_pk_fp8_f32(a, b, (int)old, true);
}
__device__ __forceinline__ f32x4 mfma8(long a, long b, f32x4 c) {
    return __builtin_amdgcn_mfma_f32_16x16x32_fp8_fp8(a, b, c, 0, 0, 0);
}

typedef __attribute__((address_space(3))) void lds_t;
typedef const __attribute__((address_space(1))) void gm_t;
#define GL16(gp, lp) __builtin_amdgcn_global_load_lds((gm_t*)(gp), (lds_t*)(lp), 16, 0, 0)

__global__ void k_init(int* cnt) { cnt[threadIdx.x] = 0; }

// Fused depthwise-conv 7x7 + LayerNorm + router. One block per (n,y) row:
// 32 tokens x 256 channels. Phase 1: conv into LDS acc[32][260] (f32).
// Phase 2: per-wave LN + top-2 router; writes fp8 xln + e01 + gates.
// Kills the xc f32 round-trip (60MB) and the scattered NHWC stores.
__global__ __launch_bounds__(512) void k_conv_lnr(const float* __restrict__ in,
                                                  const float* __restrict__ kern,
                                                  const float* __restrict__ bias,
                                                  const float* __restrict__ gamma,
                                                  const float* __restrict__ beta,
                                                  const float* __restrict__ rw,
                                                  unsigned* __restrict__ xf8,
                                                  int* __restrict__ e01,
                                                  float2* __restrict__ gates) {
    __shared__ float acc[32][260];
    __shared__ float kwl[16 * 49];
    int t = threadIdx.x;
    int n = blockIdx.x >> 5, y = blockIdx.x & 31;
    int x = t & 31, cl = t >> 5;   // cl in [0,16)

    for (int i = 0; i < 16; ++i) {
        __syncthreads();
        // stage kw for channels i*16 .. i*16+15 (784 contiguous floats)
        for (int idx = t; idx < 784; idx += 512) kwl[idx] = kern[i * 784 + idx];
        __syncthreads();
        int c = i * 16 + cl;
        const float* ip = in + (size_t)(n * CH + c) * 1024;
        const float* kwc = &kwl[cl * 49];
        float s = bias[c];
#pragma unroll
        for (int dy = -3; dy <= 3; ++dy) {
            int yy = y + dy;
            if ((unsigned)yy < 32u) {
                const float* rp = ip + yy * 32 + x;
#pragma unroll
                for (int dx = -3; dx <= 3; ++dx) {
                    int xx = x + dx;
                    if ((unsigned)xx < 32u) s = fmaf(rp[dx], kwc[(dy + 3) * 7 + (dx + 3)], s);
                }
            }
        }
        acc[x][c] = s;
    }
    __syncthreads();

    // ---- phase 2: LN + router, wave w handles tokens w*4 .. w*4+3
    int lane = t & 63, w = t >> 6;
    float4 g4 = ((const float4*)gamma)[lane];
    float4 b4 = ((const float4*)beta)[lane];
    int c0 = lane * 4;
    float4 rwv[8];  // rw rows c0..c0+3, 8 experts each
#pragma unroll
    for (int j = 0; j < 4; ++j) {
        rwv[j * 2]     = *(const float4*)(rw + (size_t)(c0 + j) * 8);
        rwv[j * 2 + 1] = *(const float4*)(rw + (size_t)(c0 + j) * 8 + 4);
    }

#pragma unroll
    for (int k = 0; k < 4; ++k) {
        int tl = w * 4 + k;
        float4 v = *(const float4*)&acc[tl][lane * 4];
        float s = v.x + v.y + v.z + v.w;
        float q = v.x * v.x + v.y * v.y + v.z * v.z + v.w * v.w;
#pragma unroll
        for (int m = 1; m < 64; m <<= 1) { s += __shfl_xor(s, m); q += __shfl_xor(q, m); }
        float mean = s * (1.0f / 256.0f);
        float var  = q * (1.0f / 256.0f) - mean * mean;
        float rstd = rsqrtf(var + 1e-6f);

        float xn[4];
        xn[0] = (v.x - mean) * rstd * g4.x + b4.x;
        xn[1] = (v.y - mean) * rstd * g4.y + b4.y;
        xn[2] = (v.z - mean) * rstd * g4.z + b4.z;
        xn[3] = (v.w - mean) * rstd * g4.w + b4.w;

        unsigned px = pk8_lo(xn[0], xn[1], 0u);
        px = pk8_hi(xn[2], xn[3], px);
        int tok = n * 1024 + y * 32 + tl;
        xf8[tok * 64 + lane] = px;

        float p[8];
#pragma unroll
        for (int e = 0; e < 8; ++e) p[e] = 0.f;
#pragma unroll
        for (int j = 0; j < 4; ++j) {
            float xv = xn[j];
            const float* r0 = (const float*)&rwv[j * 2];
#pragma unroll
            for (int e = 0; e < 8; ++e) p[e] += xv * r0[e];
        }
#pragma unroll
        for (int m = 1; m < 64; m <<= 1) {
#pragma unroll
            for (int e = 0; e < 8; ++e) p[e] += __shfl_xor(p[e], m);
        }
        if (lane == 0) {
            int e0 = 0; float l0 = p[0];
#pragma unroll
            for (int e = 1; e < 8; ++e) if (p[e] > l0) { l0 = p[e]; e0 = e; }
            int e1 = -1; float l1 = -3.4e38f;
#pragma unroll
            for (int e = 0; e < 8; ++e) if (e != e0 && p[e] > l1) { l1 = p[e]; e1 = e; }
            float tt = expf(l1 - l0);
            float w0 = 1.0f / (1.0f + tt);
            e01[tok] = e0 | (e1 << 8);
            gates[tok] = make_float2(w0, 1.0f - w0);
        }
    }
}

// Hierarchical capacity assignment.
__global__ __launch_bounds__(256) void k_assign(const int* __restrict__ e01,
                                                int* __restrict__ cnt,
                                                int* __restrict__ row_token,
                                                int2* __restrict__ slots) {
    __shared__ int lcnt[8];
    __shared__ int base[8];
    int t = threadIdx.x;
    if (t < 8) lcnt[t] = 0;
    __syncthreads();
    int tok = blockIdx.x * 256 + t;
    int ee = e01[tok];
    int e0 = ee & 255, e1 = (ee >> 8) & 255;
    int lp0 = atomicAdd(&lcnt[e0], 1);
    int lp1 = atomicAdd(&lcnt[e1], 1);
    __syncthreads();
    if (t < 8) base[t] = atomicAdd(cnt + t * CNT_STRIDE, lcnt[t]);
    __syncthreads();
    int pos0 = base[e0] + lp0;
    int pos1 = base[e1] + lp1;
    int slot0 = (pos0 < BE) ? e0 * BE + pos0 : -1;
    int slot1 = (pos1 < BE) ? e1 * BE + pos1 : -1;
    if (slot0 >= 0) row_token[slot0] = tok;
    if (slot1 >= 0) row_token[slot1] = tok;
    slots[tok] = make_int2(slot0, slot1);
}

// Transpose R x S (f32) -> S x R (fp8 e4m3), one matrix per blockIdx.z.
__global__ __launch_bounds__(256) void k_transpose8(const float* __restrict__ in,
                                                    unsigned char* __restrict__ out,
                                                    int R, int S) {
    __shared__ float tile[32][33];
    in += (size_t)blockIdx.z * R * S;
    out += (size_t)blockIdx.z * R * S;
    int tx = threadIdx.x & 31, ty = threadIdx.x >> 5;
    int sc = blockIdx.x * 32 + tx;
#pragma unroll
    for (int i = 0; i < 4; ++i) {
        int r = blockIdx.y * 32 + ty + i * 8;
        tile[ty + i * 8][tx] = in[(size_t)r * S + sc];
    }
    __syncthreads();
    int s = blockIdx.x * 32 + tx;
    int r0 = blockIdx.y * 32 + ty * 4;
    float v0 = tile[ty * 4 + 0][tx], v1 = tile[ty * 4 + 1][tx];
    float v2 = tile[ty * 4 + 2][tx], v3 = tile[ty * 4 + 3][tx];
    unsigned pk = pk8_lo(v0, v1, 0u);
    pk = pk8_hi(v2, v3, pk);
    *(unsigned*)(out + (size_t)s * R + r0) = pk;
}

// Fused expert MLP, fp8, weights LDS-staged via global_load_lds (double-buffered),
// X in VGPRs. Block = 512 threads (8 waves), 128 rows of one expert (e = bid&7).
// 16 steps of 64 hid; per step: STAGE(next) || A(hc)=W1@X -> gelu -> Hs || B(hc-1).
__global__ __launch_bounds__(512, 2) void k_mlp(const unsigned char* __restrict__ xf8,
                                                const unsigned char* __restrict__ w1t8, // [E][1024][256]
                                                const unsigned char* __restrict__ w2t8, // [E][256][1024]
                                                const float* __restrict__ b1,
                                                const float* __restrict__ b2,
                                                const int* __restrict__ cnt,
                                                const int* __restrict__ row_token,
                                                unsigned short* __restrict__ Y) {
    int bid = blockIdx.x;
    int e = bid & 7;
    int row0 = (bid >> 3) * 128;
    int nrows = min(cnt[e * CNT_STRIDE], BE);
    if (row0 >= nrows) return;

    // LDS: Xs[128][272] | W1 dbuf 2x[64][272] | W2 dbuf 2x[256][80] | H dbuf 2x[128][80]
    __shared__ char smem[131072];
    __shared__ int tokl[128];
    char* Xs   = smem;                    // 34816
    char* W1b0 = smem + 34816;            // 17408
    char* W1b1 = smem + 52224;            // 17408
    char* W2b0 = smem + 69632;            // 20480
    char* W2b1 = smem + 90112;            // 20480
    char* Hb0  = smem + 110592;           // 10240
    char* Hb1  = smem + 120832;           // 10240
    char* Ystage = smem + 34816;          // 64KB, reuses W areas after loop

    int t = threadIdx.x;
    int w = t >> 6, lane = t & 63;
    int l15 = lane & 15, l4 = lane >> 4;

    const unsigned char* w1e = w1t8 + (size_t)e * HIDN * 256;
    const unsigned char* w2e = w2t8 + (size_t)e * 256 * HIDN;

    // staging address precompute (thread-invariant across steps)
    int w1g[3], w2g[3];
#pragma unroll
    for (int rd = 0; rd < 3; ++rd) {
        int p = rd * 512 + t;
        int r1 = p / 17, c1 = p % 17; if (c1 > 15) c1 = 15;
        w1g[rd] = r1 * 256 + c1 * 16;
        int r2 = p / 5, c2 = p % 5; if (c2 > 3) c2 = 3;
        w2g[rd] = r2 * 1024 + c2 * 16;
    }
    int ldsoff[3];
#pragma unroll
    for (int rd = 0; rd < 3; ++rd) ldsoff[rd] = rd * 8192 + w * 1024;

    auto StageW1 = [&](int hc, char* dst) {
        const unsigned char* g = w1e + hc * 16384;
        GL16(g + w1g[0], dst + ldsoff[0]);
        GL16(g + w1g[1], dst + ldsoff[1]);
        if (w == 0) GL16(g + w1g[2], dst + ldsoff[2]);
    };
    auto StageW2 = [&](int hc, char* dst) {
        const unsigned char* g = w2e + hc * 64;
        GL16(g + w2g[0], dst + ldsoff[0]);
        GL16(g + w2g[1], dst + ldsoff[1]);
        if (w < 4) GL16(g + w2g[2], dst + ldsoff[2]);
    };

    if (t < 128) tokl[t] = (row0 + t < nrows) ? row_token[e * BE + row0 + t] : 0;
    __syncthreads();

    {   // stage Xs: 4 threads/row, 16B chunks; rows padded to 272B
        int r = t >> 2;
        const unsigned char* src = xf8 + (size_t)tokl[r] * 256;
#pragma unroll
        for (int i = 0; i < 4; ++i) {
            int c = (t & 3) + i * 4;
            *(int4*)(Xs + r * 272 + c * 16) = *(const int4*)(src + c * 16);
        }
    }
    StageW1(0, W1b0);
    __syncthreads();

    int hg = w & 3, tg = w >> 2;   // A-part: wave covers hid rows hg*16.., tok cols tg*64..
    // X -> regs: 4 tok-frags x 8 k-slices for this wave's tok-group
    long xr[4][8];
#pragma unroll
    for (int tf = 0; tf < 4; ++tf)
#pragma unroll
        for (int ks = 0; ks < 8; ++ks) {
            int row = tg * 64 + tf * 16 + l15;
            xr[tf][ks] = *(const long*)(Xs + row * 272 + ks * 32 + l4 * 8);
        }

    f32x4 yacc[16];
#pragma unroll
    for (int nc = 0; nc < 16; ++nc) yacc[nc] = f32x4{0.f, 0.f, 0.f, 0.f};

    // A-part: Ht[64 hid][128 tok] for chunk hc; gelu; packed b32 writes to H
    auto Apart = [&](int hc, const char* W1c, char* Hc) {
        long w1f[8];
#pragma unroll
        for (int ks = 0; ks < 8; ++ks)
            w1f[ks] = *(const long*)(W1c + (hg * 16 + l15) * 272 + ks * 32 + l4 * 8);
        f32x4 ha[4];
#pragma unroll
        for (int tf = 0; tf < 4; ++tf) ha[tf] = f32x4{0.f, 0.f, 0.f, 0.f};
#pragma unroll
        for (int ks = 0; ks < 8; ++ks)
#pragma unroll
            for (int tf = 0; tf < 4; ++tf)
                ha[tf] = mfma8(w1f[ks], xr[tf][ks], ha[tf]);
        float4 bb = *(const float4*)(b1 + e * HIDN + hc * 64 + hg * 16 + l4 * 4);
#pragma unroll
        for (int tf = 0; tf < 4; ++tf) {
            float g[4];
#pragma unroll
            for (int j = 0; j < 4; ++j) {
                float vv = ha[tf][j] + ((const float*)&bb)[j];
                float tt = vv * (1.0f + 0.044715f * vv * vv);
                g[j] = vv * __builtin_amdgcn_rcpf(1.0f + __builtin_amdgcn_exp2f(-2.3022100f * tt));
            }
            unsigned pk = pk8_lo(g[0], g[1], 0u);
            pk = pk8_hi(g[2], g[3], pk);
            int tok = tg * 64 + tf * 16 + l15;
            *(unsigned*)(Hc + tok * 80 + hg * 16 + l4 * 4) = pk;
        }
    };

    // B-part: Y[128 tok][256 out] += H(hp) @ W2(hp); wave owns tok rows w*16..
    auto Bpart = [&](const char* W2c, const char* Hp) {
        long ah[2];
#pragma unroll
        for (int ks = 0; ks < 2; ++ks)
            ah[ks] = *(const long*)(Hp + (w * 16 + l15) * 80 + ks * 32 + l4 * 8);
#pragma unroll
        for (int nc = 0; nc < 16; ++nc) {
#pragma unroll
            for (int ks = 0; ks < 2; ++ks) {
                long w2f = *(const long*)(W2c + (nc * 16 + l15) * 80 + ks * 32 + l4 * 8);
                yacc[nc] = mfma8(ah[ks], w2f, yacc[nc]);
            }
        }
    };

    for (int h2 = 0; h2 < 16; h2 += 2) {
        StageW1(h2 + 1, W1b1);
        StageW2(h2, W2b0);
        Apart(h2, W1b0, Hb0);
        if (h2 > 0) Bpart(W2b1, Hb1);
        __syncthreads();
        if (h2 + 2 < 16) StageW1(h2 + 2, W1b0);
        StageW2(h2 + 1, W2b1);
        Apart(h2 + 1, W1b1, Hb1);
        Bpart(W2b0, Hb0);
        __syncthreads();
    }
    Bpart(W2b1, Hb1);   // hid chunk 15
    __syncthreads();

    // stage Y (+b2, ->bf16) into Ystage [128][256] bf16, then coalesced copy-out
#pragma unroll
    for (int nc = 0; nc < 16; ++nc) {
        int col = nc * 16 + l15;
        float b2v = b2[e * 256 + col];
#pragma unroll
        for (int j = 0; j < 4; ++j) {
            int tok = w * 16 + l4 * 4 + j;
            *(unsigned short*)(Ystage + tok * 512 + col * 2) = f2bf(yacc[nc][j] + b2v);
        }
    }
    __syncthreads();
    {
        char* Yg = (char*)(Y + ((size_t)e * BE + row0) * 256);
#pragma unroll
        for (int i = 0; i < 8; ++i) {
            int flat = i * 8192 + t * 16;
            *(int4*)(Yg + flat) = *(const int4*)(Ystage + flat);
        }
    }
}

// Gather expert outputs (bf16), gate, add residual, write NCHW.
__global__ __launch_bounds__(256) void k_gather(const float* __restrict__ input,
                                                const unsigned short* __restrict__ Y,
                                                const int2* __restrict__ slots,
                                                const float2* __restrict__ gates,
                                                const float* __restrict__ ls,
                                                float* __restrict__ out) {
    __shared__ float acc[32][257];
    int t = threadIdx.x;
    int n = blockIdx.x >> 5, y = blockIdx.x & 31;

    {
        int tl = t & 31, chunk = t >> 5;
        int tok = n * 1024 + y * 32 + tl;
        int2  sl = slots[tok];
        float2 gw = gates[tok];
        int c0 = chunk * 32;
#pragma unroll
        for (int i = 0; i < 4; ++i) {
            int c = c0 + i * 8;
            float v[8];
#pragma unroll
            for (int k = 0; k < 8; ++k) v[k] = 0.f;
            if (sl.x >= 0) {
                bf16x8 yv = *(const bf16x8*)(Y + (size_t)sl.x * 256 + c);
#pragma unroll
                for (int k = 0; k < 8; ++k) v[k] += gw.x * bf2f((unsigned short)yv[k]);
            }
            if (sl.y >= 0) {
                bf16x8 yv = *(const bf16x8*)(Y + (size_t)sl.y * 256 + c);
#pragma unroll
                for (int k = 0; k < 8; ++k) v[k] += gw.y * bf2f((unsigned short)yv[k]);
            }
#pragma unroll
            for (int k = 0; k < 8; ++k) acc[tl][c + k] = v[k];
        }
    }
    __syncthreads();
    {
        int x = t & 31, c8 = t >> 5;
        size_t base = (size_t)n * 256 * 1024 + (size_t)y * 32 + x;
#pragma unroll
        for (int p = 0; p < 32; ++p) {
            int c = p * 8 + c8;
            size_t id = base + (size_t)c * 1024;
            out[id] = input[id] + ls[c] * acc[x][c];
        }
    }
}

extern "C" void kernel_launch(void* const* d_in, const int* in_sizes, int n_in,
                              void* d_out, int out_size, void* d_ws, size_t ws_size,
                              hipStream_t stream) {
    const float* input = (const float*)d_in[0];
    const float* dwk   = (const float*)d_in[1];
    const float* dwb   = (const float*)d_in[2];
    const float* gamma = (const float*)d_in[3];
    const float* beta  = (const float*)d_in[4];
    const float* rw    = (const float*)d_in[5];
    const float* w1    = (const float*)d_in[6];
    const float* b1    = (const float*)d_in[7];
    const float* w2    = (const float*)d_in[8];
    const float* b2    = (const float*)d_in[9];
    const float* ls    = (const float*)d_in[10];

    char* ws = (char*)d_ws;
    unsigned short* Yb   = (unsigned short*)ws;                // 40MiB bf16
    unsigned*       xf8  = (unsigned*)(ws + 83886080);         // 8MB fp8 x
    unsigned char*  w1t8 = (unsigned char*)(ws + 100663296);   // 2MB
    unsigned char*  w2t8 = (unsigned char*)(ws + 104857600);   // 2MB
    int*            rtok = (int*)(ws + 109051904);             // 320KB
    int2*           slots = (int2*)(ws + 109379584);           // 256KB
    float2*         gates = (float2*)(ws + 109641728);         // 256KB
    int*            e01  = (int*)(ws + 109903872);             // 128KB
    int*            cnt  = (int*)(ws + 110035968);             // 8*64 ints

    k_init<<<1, NE * CNT_STRIDE, 0, stream>>>(cnt);
    k_conv_lnr<<<1024, 512, 0, stream>>>(input, dwk, dwb, gamma, beta, rw, xf8, e01, gates);
    k_assign<<<128, 256, 0, stream>>>(e01, cnt, rtok, slots);
    k_transpose8<<<dim3(32, 8, 8), 256, 0, stream>>>(w1, w1t8, 256, 1024);  // [E][1024][256]
    k_transpose8<<<dim3(8, 32, 8), 256, 0, stream>>>(w2, w2t8, 1024, 256);  // [E][256][1024]
    k_mlp<<<640, 512, 0, stream>>>((const unsigned char*)xf8, w1t8, w2t8, b1, b2, cnt, rtok, Yb);
    k_gather<<<1024, 256, 0, stream>>>(input, Yb, slots, gates, ls, (float*)d_out);
}

// Round 9
// 230.921 us; speedup vs baseline: 1.8820x; 1.8820x over previous
//
#include <hip/hip_runtime.h>
#include <math.h>

#define TOK 32768
#define CH  256
#define HIDN 1024
#define NE  8
#define BE  10240
#define CNT_STRIDE 64

typedef __attribute__((ext_vector_type(8))) short bf16x8;
typedef __attribute__((ext_vector_type(4))) float f32x4;

__device__ __forceinline__ unsigned short f2bf(float f) {
    unsigned u = __builtin_bit_cast(unsigned, f);
    unsigned r = 0x7FFFu + ((u >> 16) & 1u);
    return (unsigned short)((u + r) >> 16);
}
__device__ __forceinline__ float bf2f(unsigned short u) {
    return __builtin_bit_cast(float, (unsigned)u << 16);
}
__device__ __forceinline__ unsigned pk8_lo(float a, float b, unsigned old) {
    return (unsigned)__builtin_amdgcn_cvt_pk_fp8_f32(a, b, (int)old, false);
}
__device__ __forceinline__ unsigned pk8_hi(float a, float b, unsigned old) {
    return (unsigned)__builtin_amdgcn_cvt_pk_fp8_f32(a, b, (int)old, true);
}
__device__ __forceinline__ f32x4 mfma8(long a, long b, f32x4 c) {
    return __builtin_amdgcn_mfma_f32_16x16x32_fp8_fp8(a, b, c, 0, 0, 0);
}

typedef __attribute__((address_space(3))) void lds_t;
typedef const __attribute__((address_space(1))) void gm_t;
#define GL16(gp, lp) __builtin_amdgcn_global_load_lds((gm_t*)(gp), (lds_t*)(lp), 16, 0, 0)

__global__ void k_init(int* cnt) { cnt[threadIdx.x] = 0; }

// Depthwise 7x7 conv + bias. Block = one (n,c) image; image staged to LDS via
// global_load_lds; each thread computes a 4-output vertical column (tap reuse
// 2.8x: 70 LDS reads for 196 FMAs). Output NCHW bf16, fully coalesced.
__global__ __launch_bounds__(256) void k_conv(const float* __restrict__ in,
                                              const float* __restrict__ kern,
                                              const float* __restrict__ bias,
                                              unsigned short* __restrict__ xcb) {
    __shared__ float img[1024];
    __shared__ float kwl[49];
    int t = threadIdx.x;
    int bid = blockIdx.x;          // bid = n*256 + c  (matches NCHW layout)
    int c = bid & 255;

    GL16(in + (size_t)bid * 1024 + t * 4, (char*)img + t * 16);
    if (t < 49) kwl[t] = kern[c * 49 + t];
    __syncthreads();

    int x = t & 31, y0 = (t >> 5) * 4;
    float b0 = bias[c];
    float acc[4] = {b0, b0, b0, b0};
#pragma unroll
    for (int rr = 0; rr < 10; ++rr) {
        int r = y0 - 3 + rr;
        if ((unsigned)r < 32u) {
#pragma unroll
            for (int dx = -3; dx <= 3; ++dx) {
                int xx = x + dx;
                if ((unsigned)xx < 32u) {
                    float v = img[r * 32 + xx];
#pragma unroll
                    for (int o = 0; o < 4; ++o) {
                        int jr = rr - o;           // dy+3 for output y0+o
                        if (0 <= jr && jr <= 6)
                            acc[o] = fmaf(v, kwl[jr * 7 + (dx + 3)], acc[o]);
                    }
                }
            }
        }
    }
#pragma unroll
    for (int o = 0; o < 4; ++o)
        xcb[(size_t)bid * 1024 + (y0 + o) * 32 + x] = f2bf(acc[o]);
}

// LN + router: block = (n,y) row (32 tokens x 256 ch). Loads 16 bf16/thread
// up-front (independent coalesced), LDS transpose, then per-wave LN + top-2.
__global__ __launch_bounds__(512) void k_lnr(const unsigned short* __restrict__ xcb,
                                             const float* __restrict__ gamma,
                                             const float* __restrict__ beta,
                                             const float* __restrict__ rw,
                                             unsigned* __restrict__ xf8,
                                             int* __restrict__ e01,
                                             float2* __restrict__ gates) {
    __shared__ float acc[32][260];
    int t = threadIdx.x;
    int n = blockIdx.x >> 5, y = blockIdx.x & 31;
    int x = t & 31, ch = t >> 5;   // ch in [0,16)

    float vals[16];
#pragma unroll
    for (int i = 0; i < 16; ++i) {
        int c = i * 16 + ch;
        vals[i] = bf2f(xcb[((size_t)(n * 256 + c)) * 1024 + y * 32 + x]);
    }
#pragma unroll
    for (int i = 0; i < 16; ++i) acc[x][i * 16 + ch] = vals[i];
    __syncthreads();

    // ---- LN + router, wave w handles tokens w*4 .. w*4+3
    int lane = t & 63, w = t >> 6;
    float4 g4 = ((const float4*)gamma)[lane];
    float4 b4 = ((const float4*)beta)[lane];
    int c0 = lane * 4;
    float4 rwv[8];
#pragma unroll
    for (int j = 0; j < 4; ++j) {
        rwv[j * 2]     = *(const float4*)(rw + (size_t)(c0 + j) * 8);
        rwv[j * 2 + 1] = *(const float4*)(rw + (size_t)(c0 + j) * 8 + 4);
    }

#pragma unroll
    for (int k = 0; k < 4; ++k) {
        int tl = w * 4 + k;
        float4 v = *(const float4*)&acc[tl][lane * 4];
        float s = v.x + v.y + v.z + v.w;
        float q = v.x * v.x + v.y * v.y + v.z * v.z + v.w * v.w;
#pragma unroll
        for (int m = 1; m < 64; m <<= 1) { s += __shfl_xor(s, m); q += __shfl_xor(q, m); }
        float mean = s * (1.0f / 256.0f);
        float var  = q * (1.0f / 256.0f) - mean * mean;
        float rstd = rsqrtf(var + 1e-6f);

        float xn[4];
        xn[0] = (v.x - mean) * rstd * g4.x + b4.x;
        xn[1] = (v.y - mean) * rstd * g4.y + b4.y;
        xn[2] = (v.z - mean) * rstd * g4.z + b4.z;
        xn[3] = (v.w - mean) * rstd * g4.w + b4.w;

        unsigned px = pk8_lo(xn[0], xn[1], 0u);
        px = pk8_hi(xn[2], xn[3], px);
        int tok = n * 1024 + y * 32 + tl;
        xf8[tok * 64 + lane] = px;

        float p[8];
#pragma unroll
        for (int e = 0; e < 8; ++e) p[e] = 0.f;
#pragma unroll
        for (int j = 0; j < 4; ++j) {
            float xv = xn[j];
            const float* r0 = (const float*)&rwv[j * 2];
#pragma unroll
            for (int e = 0; e < 8; ++e) p[e] += xv * r0[e];
        }
#pragma unroll
        for (int m = 1; m < 64; m <<= 1) {
#pragma unroll
            for (int e = 0; e < 8; ++e) p[e] += __shfl_xor(p[e], m);
        }
        if (lane == 0) {
            int e0 = 0; float l0 = p[0];
#pragma unroll
            for (int e = 1; e < 8; ++e) if (p[e] > l0) { l0 = p[e]; e0 = e; }
            int e1 = -1; float l1 = -3.4e38f;
#pragma unroll
            for (int e = 0; e < 8; ++e) if (e != e0 && p[e] > l1) { l1 = p[e]; e1 = e; }
            float tt = expf(l1 - l0);
            float w0 = 1.0f / (1.0f + tt);
            e01[tok] = e0 | (e1 << 8);
            gates[tok] = make_float2(w0, 1.0f - w0);
        }
    }
}

// Hierarchical capacity assignment.
__global__ __launch_bounds__(256) void k_assign(const int* __restrict__ e01,
                                                int* __restrict__ cnt,
                                                int* __restrict__ row_token,
                                                int2* __restrict__ slots) {
    __shared__ int lcnt[8];
    __shared__ int base[8];
    int t = threadIdx.x;
    if (t < 8) lcnt[t] = 0;
    __syncthreads();
    int tok = blockIdx.x * 256 + t;
    int ee = e01[tok];
    int e0 = ee & 255, e1 = (ee >> 8) & 255;
    int lp0 = atomicAdd(&lcnt[e0], 1);
    int lp1 = atomicAdd(&lcnt[e1], 1);
    __syncthreads();
    if (t < 8) base[t] = atomicAdd(cnt + t * CNT_STRIDE, lcnt[t]);
    __syncthreads();
    int pos0 = base[e0] + lp0;
    int pos1 = base[e1] + lp1;
    int slot0 = (pos0 < BE) ? e0 * BE + pos0 : -1;
    int slot1 = (pos1 < BE) ? e1 * BE + pos1 : -1;
    if (slot0 >= 0) row_token[slot0] = tok;
    if (slot1 >= 0) row_token[slot1] = tok;
    slots[tok] = make_int2(slot0, slot1);
}

// Transpose R x S (f32) -> S x R (fp8 e4m3), one matrix per blockIdx.z.
__global__ __launch_bounds__(256) void k_transpose8(const float* __restrict__ in,
                                                    unsigned char* __restrict__ out,
                                                    int R, int S) {
    __shared__ float tile[32][33];
    in += (size_t)blockIdx.z * R * S;
    out += (size_t)blockIdx.z * R * S;
    int tx = threadIdx.x & 31, ty = threadIdx.x >> 5;
    int sc = blockIdx.x * 32 + tx;
#pragma unroll
    for (int i = 0; i < 4; ++i) {
        int r = blockIdx.y * 32 + ty + i * 8;
        tile[ty + i * 8][tx] = in[(size_t)r * S + sc];
    }
    __syncthreads();
    int s = blockIdx.x * 32 + tx;
    int r0 = blockIdx.y * 32 + ty * 4;
    float v0 = tile[ty * 4 + 0][tx], v1 = tile[ty * 4 + 1][tx];
    float v2 = tile[ty * 4 + 2][tx], v3 = tile[ty * 4 + 3][tx];
    unsigned pk = pk8_lo(v0, v1, 0u);
    pk = pk8_hi(v2, v3, pk);
    *(unsigned*)(out + (size_t)s * R + r0) = pk;
}

// Fused expert MLP, fp8, weights LDS-staged via global_load_lds (double-buffered),
// X in VGPRs. Block = 512 threads (8 waves), 128 rows of one expert (e = bid&7).
// 16 steps of 64 hid; per step: STAGE(next) || A(hc)=W1@X -> gelu -> Hs || B(hc-1).
__global__ __launch_bounds__(512, 2) void k_mlp(const unsigned char* __restrict__ xf8,
                                                const unsigned char* __restrict__ w1t8, // [E][1024][256]
                                                const unsigned char* __restrict__ w2t8, // [E][256][1024]
                                                const float* __restrict__ b1,
                                                const float* __restrict__ b2,
                                                const int* __restrict__ cnt,
                                                const int* __restrict__ row_token,
                                                unsigned short* __restrict__ Y) {
    int bid = blockIdx.x;
    int e = bid & 7;
    int row0 = (bid >> 3) * 128;
    int nrows = min(cnt[e * CNT_STRIDE], BE);
    if (row0 >= nrows) return;

    // LDS: Xs[128][272] | W1 dbuf 2x[64][272] | W2 dbuf 2x[256][80] | H dbuf 2x[128][80]
    __shared__ char smem[131072];
    __shared__ int tokl[128];
    char* Xs   = smem;                    // 34816
    char* W1b0 = smem + 34816;            // 17408
    char* W1b1 = smem + 52224;            // 17408
    char* W2b0 = smem + 69632;            // 20480
    char* W2b1 = smem + 90112;            // 20480
    char* Hb0  = smem + 110592;           // 10240
    char* Hb1  = smem + 120832;           // 10240
    char* Ystage = smem + 34816;          // 64KB, reuses W areas after loop

    int t = threadIdx.x;
    int w = t >> 6, lane = t & 63;
    int l15 = lane & 15, l4 = lane >> 4;

    const unsigned char* w1e = w1t8 + (size_t)e * HIDN * 256;
    const unsigned char* w2e = w2t8 + (size_t)e * 256 * HIDN;

    // staging address precompute (thread-invariant across steps)
    int w1g[3], w2g[3];
#pragma unroll
    for (int rd = 0; rd < 3; ++rd) {
        int p = rd * 512 + t;
        int r1 = p / 17, c1 = p % 17; if (c1 > 15) c1 = 15;
        w1g[rd] = r1 * 256 + c1 * 16;
        int r2 = p / 5, c2 = p % 5; if (c2 > 3) c2 = 3;
        w2g[rd] = r2 * 1024 + c2 * 16;
    }
    int ldsoff[3];
#pragma unroll
    for (int rd = 0; rd < 3; ++rd) ldsoff[rd] = rd * 8192 + w * 1024;

    auto StageW1 = [&](int hc, char* dst) {
        const unsigned char* g = w1e + hc * 16384;
        GL16(g + w1g[0], dst + ldsoff[0]);
        GL16(g + w1g[1], dst + ldsoff[1]);
        if (w == 0) GL16(g + w1g[2], dst + ldsoff[2]);
    };
    auto StageW2 = [&](int hc, char* dst) {
        const unsigned char* g = w2e + hc * 64;
        GL16(g + w2g[0], dst + ldsoff[0]);
        GL16(g + w2g[1], dst + ldsoff[1]);
        if (w < 4) GL16(g + w2g[2], dst + ldsoff[2]);
    };

    if (t < 128) tokl[t] = (row0 + t < nrows) ? row_token[e * BE + row0 + t] : 0;
    __syncthreads();

    {   // stage Xs: 4 threads/row, 16B chunks; rows padded to 272B
        int r = t >> 2;
        const unsigned char* src = xf8 + (size_t)tokl[r] * 256;
#pragma unroll
        for (int i = 0; i < 4; ++i) {
            int c = (t & 3) + i * 4;
            *(int4*)(Xs + r * 272 + c * 16) = *(const int4*)(src + c * 16);
        }
    }
    StageW1(0, W1b0);
    __syncthreads();

    int hg = w & 3, tg = w >> 2;   // A-part: wave covers hid rows hg*16.., tok cols tg*64..
    // X -> regs: 4 tok-frags x 8 k-slices for this wave's tok-group
    long xr[4][8];
#pragma unroll
    for (int tf = 0; tf < 4; ++tf)
#pragma unroll
        for (int ks = 0; ks < 8; ++ks) {
            int row = tg * 64 + tf * 16 + l15;
            xr[tf][ks] = *(const long*)(Xs + row * 272 + ks * 32 + l4 * 8);
        }

    f32x4 yacc[16];
#pragma unroll
    for (int nc = 0; nc < 16; ++nc) yacc[nc] = f32x4{0.f, 0.f, 0.f, 0.f};

    // A-part: Ht[64 hid][128 tok] for chunk hc; gelu; packed b32 writes to H
    auto Apart = [&](int hc, const char* W1c, char* Hc) {
        long w1f[8];
#pragma unroll
        for (int ks = 0; ks < 8; ++ks)
            w1f[ks] = *(const long*)(W1c + (hg * 16 + l15) * 272 + ks * 32 + l4 * 8);
        f32x4 ha[4];
#pragma unroll
        for (int tf = 0; tf < 4; ++tf) ha[tf] = f32x4{0.f, 0.f, 0.f, 0.f};
#pragma unroll
        for (int ks = 0; ks < 8; ++ks)
#pragma unroll
            for (int tf = 0; tf < 4; ++tf)
                ha[tf] = mfma8(w1f[ks], xr[tf][ks], ha[tf]);
        float4 bb = *(const float4*)(b1 + e * HIDN + hc * 64 + hg * 16 + l4 * 4);
#pragma unroll
        for (int tf = 0; tf < 4; ++tf) {
            float g[4];
#pragma unroll
            for (int j = 0; j < 4; ++j) {
                float vv = ha[tf][j] + ((const float*)&bb)[j];
                float tt = vv * (1.0f + 0.044715f * vv * vv);
                g[j] = vv * __builtin_amdgcn_rcpf(1.0f + __builtin_amdgcn_exp2f(-2.3022100f * tt));
            }
            unsigned pk = pk8_lo(g[0], g[1], 0u);
            pk = pk8_hi(g[2], g[3], pk);
            int tok = tg * 64 + tf * 16 + l15;
            *(unsigned*)(Hc + tok * 80 + hg * 16 + l4 * 4) = pk;
        }
    };

    // B-part: Y[128 tok][256 out] += H(hp) @ W2(hp); wave owns tok rows w*16..
    auto Bpart = [&](const char* W2c, const char* Hp) {
        long ah[2];
#pragma unroll
        for (int ks = 0; ks < 2; ++ks)
            ah[ks] = *(const long*)(Hp + (w * 16 + l15) * 80 + ks * 32 + l4 * 8);
#pragma unroll
        for (int nc = 0; nc < 16; ++nc) {
#pragma unroll
            for (int ks = 0; ks < 2; ++ks) {
                long w2f = *(const long*)(W2c + (nc * 16 + l15) * 80 + ks * 32 + l4 * 8);
                yacc[nc] = mfma8(ah[ks], w2f, yacc[nc]);
            }
        }
    };

    for (int h2 = 0; h2 < 16; h2 += 2) {
        StageW1(h2 + 1, W1b1);
        StageW2(h2, W2b0);
        Apart(h2, W1b0, Hb0);
        if (h2 > 0) Bpart(W2b1, Hb1);
        __syncthreads();
        if (h2 + 2 < 16) StageW1(h2 + 2, W1b0);
        StageW2(h2 + 1, W2b1);
        Apart(h2 + 1, W1b1, Hb1);
        Bpart(W2b0, Hb0);
        __syncthreads();
    }
    Bpart(W2b1, Hb1);   // hid chunk 15
    __syncthreads();

    // stage Y (+b2, ->bf16) into Ystage [128][256] bf16, then coalesced copy-out
#pragma unroll
    for (int nc = 0; nc < 16; ++nc) {
        int col = nc * 16 + l15;
        float b2v = b2[e * 256 + col];
#pragma unroll
        for (int j = 0; j < 4; ++j) {
            int tok = w * 16 + l4 * 4 + j;
            *(unsigned short*)(Ystage + tok * 512 + col * 2) = f2bf(yacc[nc][j] + b2v);
        }
    }
    __syncthreads();
    {
        char* Yg = (char*)(Y + ((size_t)e * BE + row0) * 256);
#pragma unroll
        for (int i = 0; i < 8; ++i) {
            int flat = i * 8192 + t * 16;
            *(int4*)(Yg + flat) = *(const int4*)(Ystage + flat);
        }
    }
}

// Gather expert outputs (bf16), gate, add residual, write NCHW.
__global__ __launch_bounds__(256) void k_gather(const float* __restrict__ input,
                                                const unsigned short* __restrict__ Y,
                                                const int2* __restrict__ slots,
                                                const float2* __restrict__ gates,
                                                const float* __restrict__ ls,
                                                float* __restrict__ out) {
    __shared__ float acc[32][257];
    int t = threadIdx.x;
    int n = blockIdx.x >> 5, y = blockIdx.x & 31;

    {
        int tl = t & 31, chunk = t >> 5;
        int tok = n * 1024 + y * 32 + tl;
        int2  sl = slots[tok];
        float2 gw = gates[tok];
        int c0 = chunk * 32;
#pragma unroll
        for (int i = 0; i < 4; ++i) {
            int c = c0 + i * 8;
            float v[8];
#pragma unroll
            for (int k = 0; k < 8; ++k) v[k] = 0.f;
            if (sl.x >= 0) {
                bf16x8 yv = *(const bf16x8*)(Y + (size_t)sl.x * 256 + c);
#pragma unroll
                for (int k = 0; k < 8; ++k) v[k] += gw.x * bf2f((unsigned short)yv[k]);
            }
            if (sl.y >= 0) {
                bf16x8 yv = *(const bf16x8*)(Y + (size_t)sl.y * 256 + c);
#pragma unroll
                for (int k = 0; k < 8; ++k) v[k] += gw.y * bf2f((unsigned short)yv[k]);
            }
#pragma unroll
            for (int k = 0; k < 8; ++k) acc[tl][c + k] = v[k];
        }
    }
    __syncthreads();
    {
        int x = t & 31, c8 = t >> 5;
        size_t base = (size_t)n * 256 * 1024 + (size_t)y * 32 + x;
#pragma unroll
        for (int p = 0; p < 32; ++p) {
            int c = p * 8 + c8;
            size_t id = base + (size_t)c * 1024;
            out[id] = input[id] + ls[c] * acc[x][c];
        }
    }
}

extern "C" void kernel_launch(void* const* d_in, const int* in_sizes, int n_in,
                              void* d_out, int out_size, void* d_ws, size_t ws_size,
                              hipStream_t stream) {
    const float* input = (const float*)d_in[0];
    const float* dwk   = (const float*)d_in[1];
    const float* dwb   = (const float*)d_in[2];
    const float* gamma = (const float*)d_in[3];
    const float* beta  = (const float*)d_in[4];
    const float* rw    = (const float*)d_in[5];
    const float* w1    = (const float*)d_in[6];
    const float* b1    = (const float*)d_in[7];
    const float* w2    = (const float*)d_in[8];
    const float* b2    = (const float*)d_in[9];
    const float* ls    = (const float*)d_in[10];

    char* ws = (char*)d_ws;
    // xcb (64MiB bf16 NCHW conv out) aliases Yb (40MiB): xcb dead before k_mlp writes Yb.
    unsigned short* xcb  = (unsigned short*)ws;
    unsigned short* Yb   = (unsigned short*)ws;
    unsigned*       xf8  = (unsigned*)(ws + 83886080);         // 8MB fp8 x
    unsigned char*  w1t8 = (unsigned char*)(ws + 100663296);   // 2MB
    unsigned char*  w2t8 = (unsigned char*)(ws + 104857600);   // 2MB
    int*            rtok = (int*)(ws + 109051904);             // 320KB
    int2*           slots = (int2*)(ws + 109379584);           // 256KB
    float2*         gates = (float2*)(ws + 109641728);         // 256KB
    int*            e01  = (int*)(ws + 109903872);             // 128KB
    int*            cnt  = (int*)(ws + 110035968);             // 8*64 ints

    k_init<<<1, NE * CNT_STRIDE, 0, stream>>>(cnt);
    k_conv<<<8192, 256, 0, stream>>>(input, dwk, dwb, xcb);
    k_lnr<<<1024, 512, 0, stream>>>(xcb, gamma, beta, rw, xf8, e01, gates);
    k_assign<<<128, 256, 0, stream>>>(e01, cnt, rtok, slots);
    k_transpose8<<<dim3(32, 8, 8), 256, 0, stream>>>(w1, w1t8, 256, 1024);  // [E][1024][256]
    k_transpose8<<<dim3(8, 32, 8), 256, 0, stream>>>(w2, w2t8, 1024, 256);  // [E][256][1024]
    k_mlp<<<640, 512, 0, stream>>>((const unsigned char*)xf8, w1t8, w2t8, b1, b2, cnt, rtok, Yb);
    k_gather<<<1024, 256, 0, stream>>>(input, Yb, slots, gates, ls, (float*)d_out);
}